// Round 8
// baseline (42.012 us; speedup 1.0000x reference)
//
#include <hip/hip_runtime.h>
#include <math.h>

// Problem dims (fixed by the reference)
#define F_  26
#define V_  100000
#define E_  16
#define B_  16384
#define ND_ 13
#define D_  4
#define H_  128
#define T_  8
#define NKS 14       // K-steps of 32 (K padded 429 -> 448)
#define XSTR 456     // x_lds row stride in bf16 (448 + 8 pad)
#define FSTR 136     // feat_lds row stride in bf16 (128 + 8 pad)
#define BB  32       // batch rows per block
#define NT  512      // threads per block (8 waves; 2 blocks/CU -> 16 waves/CU)

typedef short bf16x8 __attribute__((ext_vector_type(8)));
typedef float f32x4  __attribute__((ext_vector_type(4)));

__device__ __forceinline__ unsigned short f2bf(float f) {
    unsigned int u = __float_as_uint(f);
    u += 0x7FFF + ((u >> 16) & 1);   // RNE
    return (unsigned short)(u >> 16);
}

union BF8 { bf16x8 v; unsigned short us[8]; };

// ---------- single fused kernel: in-register W-pack + gather + 2x MFMA GEMM ----------
__global__ __launch_bounds__(NT, 4)
void sb_fused_kernel(const int* __restrict__ sparse_ids,
                     const float* __restrict__ dense,
                     const int* __restrict__ domain_id,
                     const float* __restrict__ emb_tables,
                     const float* __restrict__ W_bottom,
                     const float* __restrict__ b_bottom,
                     const float* __restrict__ tower_W1,
                     const float* __restrict__ tower_b1,
                     const float* __restrict__ tower_W2,
                     const float* __restrict__ tower_b2,
                     float* __restrict__ out)
{
    __shared__ unsigned short x_lds[BB][XSTR];     // 29,184 B
    __shared__ unsigned short feat_lds[BB][FSTR];  //  8,704 B

    const int t  = threadIdx.x;
    const int r0 = blockIdx.x * BB;
    const int l   = t & 63;
    const int w   = t >> 6;        // 0..7
    const int lhi = l >> 4;        // 0..3
    const int llo = l & 15;

    // ---- step 1: issue the 7 sparse-id loads (cold HBM; latency hides under pack) ----
    int id_[7];
#pragma unroll
    for (int it = 0; it < 7; ++it) {
        const int idx = t + (it << 9);
        if (it < 6 || idx < BB * F_ * 4) {
            const int rf  = idx >> 2;
            const int row = rf / F_;
            const int f   = rf - row * F_;
            id_[it] = sparse_ids[(r0 + row) * F_ + f];
        }
    }

    // ---- step 2: in-register pack of this wave's 14 W_bottom B-fragments ----
    // lane l, frag ks, elem j = W[ks*32 + lhi*8 + j][w*16 + llo]  (0 for row >= 429)
    const int c = (w << 4) + llo;
    bf16x8 bfrag[NKS];
#pragma unroll
    for (int ks = 0; ks < NKS; ++ks) {
        const int rbase = (ks << 5) + (lhi << 3);
        BF8 u;
#pragma unroll
        for (int j = 0; j < 8; ++j) {
            const int r = rbase + j;
            const float f = (r < 429) ? W_bottom[(r << 7) + c] : 0.f;
            u.us[j] = f2bf(f);
        }
        bfrag[ks] = u.v;
    }

    // ---- step 3 (waves 0-3): in-register pack of the 4 tower-W1 fragments ----
    // frag (ks2, nt=w&1): lane l elem j = W1_all[ks2*32 + lhi*8 + j][nt*16 + llo]
    //   where W1_all[h][d*8+tt] = tower_W1[d][h][tt]
    bf16x8 tfrag[4];
    if (w < 4) {
        const int ct = ((w & 1) << 4) + llo;   // global tower col = d*8 + tt
        const int d  = ct >> 3;
        const int tt = ct & 7;
#pragma unroll
        for (int ks2 = 0; ks2 < 4; ++ks2) {
            const int hbase = (ks2 << 5) + (lhi << 3);
            BF8 u;
#pragma unroll
            for (int j = 0; j < 8; ++j) {
                u.us[j] = f2bf(tower_W1[(d << 10) + ((hbase + j) << 3) + tt]);
            }
            tfrag[ks2] = u.v;
        }
    }

    // ---- step 4: gather embeddings (fp32 -> bf16) into LDS, two batches ----
    // 3328 float4-tasks; 4 lanes share one 64B embedding row.
    {
        float4 va[4];
#pragma unroll
        for (int it = 0; it < 4; ++it) {       // tasks 0..3: always valid
            const int idx = t + (it << 9);
            const int q   = idx & 3;
            const int rf  = idx >> 2;
            const int row = rf / F_;
            const int f   = rf - row * F_;
            va[it] = *reinterpret_cast<const float4*>(
                emb_tables + ((size_t)f * V_ + (size_t)id_[it]) * E_ + (q << 2));
        }
        float4 vb[3];
#pragma unroll
        for (int it = 4; it < 7; ++it) {       // tasks 4,5 valid; 6 guarded
            const int idx = t + (it << 9);
            if (it < 6 || idx < BB * F_ * 4) {
                const int q   = idx & 3;
                const int rf  = idx >> 2;
                const int row = rf / F_;
                const int f   = rf - row * F_;
                vb[it - 4] = *reinterpret_cast<const float4*>(
                    emb_tables + ((size_t)f * V_ + (size_t)id_[it]) * E_ + (q << 2));
            }
        }
#pragma unroll
        for (int it = 0; it < 4; ++it) {
            const int idx = t + (it << 9);
            const int q   = idx & 3;
            const int rf  = idx >> 2;
            const int row = rf / F_;
            const int f   = rf - row * F_;
            ushort4 b;
            b.x = f2bf(va[it].x); b.y = f2bf(va[it].y);
            b.z = f2bf(va[it].z); b.w = f2bf(va[it].w);
            *reinterpret_cast<ushort4*>(&x_lds[row][(f << 4) + (q << 2)]) = b;
        }
#pragma unroll
        for (int it = 4; it < 7; ++it) {
            const int idx = t + (it << 9);
            if (it < 6 || idx < BB * F_ * 4) {
                const int q   = idx & 3;
                const int rf  = idx >> 2;
                const int row = rf / F_;
                const int f   = rf - row * F_;
                ushort4 b;
                b.x = f2bf(vb[it - 4].x); b.y = f2bf(vb[it - 4].y);
                b.z = f2bf(vb[it - 4].z); b.w = f2bf(vb[it - 4].w);
                *reinterpret_cast<ushort4*>(&x_lds[row][(f << 4) + (q << 2)]) = b;
            }
        }
    }
    // dense -> cols 416..428 (bf16), zero-pad cols 429..447 (2 tasks/thread)
#pragma unroll
    for (int it = 0; it < 2; ++it) {
        const int idx = t + (it << 9);
        const int row = idx >> 5;
        const int cc  = 416 + (idx & 31);
        x_lds[row][cc] = (cc < 429) ? f2bf(dense[(r0 + row) * ND_ + (cc - 416)]) : 0;
    }
    __syncthreads();

    // ---- Phase B: bottom GEMM via MFMA  feat = relu(X @ W + b) ----
    // wave w owns ntile w (cols 16w..16w+15), both mtiles (rows 0..31)
    f32x4 acc0 = {0.f,0.f,0.f,0.f};
    f32x4 acc1 = acc0;

#pragma unroll
    for (int ks = 0; ks < NKS; ++ks) {
        const int ko = (ks << 5) + (lhi << 3);
        const bf16x8 a0 = *reinterpret_cast<const bf16x8*>(&x_lds[llo][ko]);
        const bf16x8 a1 = *reinterpret_cast<const bf16x8*>(&x_lds[16 + llo][ko]);
        acc0 = __builtin_amdgcn_mfma_f32_16x16x32_bf16(a0, bfrag[ks], acc0, 0, 0, 0);
        acc1 = __builtin_amdgcn_mfma_f32_16x16x32_bf16(a1, bfrag[ks], acc1, 0, 0, 0);
    }

    {   // epilogue: bias + relu -> feat_lds (bf16, A-fragment-friendly layout)
        const float bias = b_bottom[c];
#pragma unroll
        for (int i = 0; i < 4; ++i) {
            const int r = (lhi << 2) + i;
            feat_lds[r][c]      = f2bf(fmaxf(acc0[i] + bias, 0.f));
            feat_lds[16 + r][c] = f2bf(fmaxf(acc1[i] + bias, 0.f));
        }
    }
    __syncthreads();

    // ---- Phase C: tower via MFMA over all 4 domains (waves 0..3) ----
    // h_all[32 rows][32 cols], col = d*8 + tt.  wave w: mtile = w>>1, ntile = w&1
    if (w < 4) {
        const int mt = w >> 1;
        const int nt = w & 1;
        f32x4 acc = {0.f,0.f,0.f,0.f};
#pragma unroll
        for (int ks2 = 0; ks2 < 4; ++ks2) {
            const bf16x8 a = *reinterpret_cast<const bf16x8*>(
                &feat_lds[(mt << 4) + llo][(ks2 << 5) + (lhi << 3)]);
            acc = __builtin_amdgcn_mfma_f32_16x16x32_bf16(a, tfrag[ks2], acc, 0, 0, 0);
        }
        const int col    = (nt << 4) + llo;    // global tower col = d*8 + tt
        const float b1v  = tower_b1[col];
        const float w2v  = tower_W2[col];
        const int  dlane = (nt << 1) + (llo >> 3);
        const bool writer = ((llo & 7) == 0);
#pragma unroll
        for (int i = 0; i < 4; ++i) {
            float v = fmaxf(acc[i] + b1v, 0.f) * w2v;
            v += __shfl_xor(v, 1);
            v += __shfl_xor(v, 2);
            v += __shfl_xor(v, 4);
            if (writer) {
                const int r   = (mt << 4) + (lhi << 2) + i;
                const int d_r = domain_id[r0 + r];
                if (d_r == dlane) {
                    out[r0 + r] = 1.f / (1.f + expf(-(v + tower_b2[d_r])));
                }
            }
        }
    }
}

extern "C" void kernel_launch(void* const* d_in, const int* in_sizes, int n_in,
                              void* d_out, int out_size, void* d_ws, size_t ws_size,
                              hipStream_t stream) {
    const int*   sparse_ids = (const int*)  d_in[0];
    const float* dense      = (const float*)d_in[1];
    const int*   domain_id  = (const int*)  d_in[2];
    const float* emb_tables = (const float*)d_in[3];
    const float* W_bottom   = (const float*)d_in[4];
    const float* b_bottom   = (const float*)d_in[5];
    const float* tower_W1   = (const float*)d_in[6];
    const float* tower_b1   = (const float*)d_in[7];
    const float* tower_W2   = (const float*)d_in[8];
    const float* tower_b2   = (const float*)d_in[9];
    float* out = (float*)d_out;

    sb_fused_kernel<<<B_ / BB, NT, 0, stream>>>(
        sparse_ids, dense, domain_id, emb_tables,
        W_bottom, b_bottom, tower_W1, tower_b1, tower_W2, tower_b2, out);
}

// Round 9
// 23.698 us; speedup vs baseline: 1.7728x; 1.7728x over previous
//
#include <hip/hip_runtime.h>
#include <math.h>

// Problem dims (fixed by the reference)
#define F_  26
#define V_  100000
#define E_  16
#define B_  16384
#define ND_ 13
#define D_  4
#define H_  128
#define T_  8
#define NKS 14       // K-steps of 32 (K padded 429 -> 448)
#define NPRE 7       // B-fragments preloaded to registers before Phase A
#define XSTR 456     // x_lds row stride in bf16 (448 + 8 pad)
#define FSTR 136     // feat_lds row stride in bf16 (128 + 8 pad)
#define BB  32       // batch rows per block
#define NT  512      // threads per block
#define NGT 7        // gather tasks per thread (ceil(3328/512))

typedef short bf16x8 __attribute__((ext_vector_type(8)));
typedef float f32x4  __attribute__((ext_vector_type(4)));

__device__ __forceinline__ unsigned short f2bf(float f) {
    unsigned int u = __float_as_uint(f);
    u += 0x7FFF + ((u >> 16) & 1);   // RNE
    return (unsigned short)(u >> 16);
}

// ---------- prep v2: coalesced W_bottom pack + tower_W1 pack ----------
// wsB: fragment (ks, n): lane l elem j = W[ks*32 + (l>>4)*8 + j][n*16 + (l&15)]
// Read side is fully coalesced: thread tid handles row k = tid>>5, cols 4*(tid&31)..+3
// (float4 row read), then scatters 4 bf16 into fragment layout (L2 writes).
__global__ __launch_bounds__(256)
void prep_kernel(const float* __restrict__ W_bottom,
                 const float* __restrict__ tower_W1,
                 unsigned short* __restrict__ wsB,
                 unsigned short* __restrict__ wsT1)
{
    const int tid = blockIdx.x * 256 + threadIdx.x;
    if (tid < 448 * 32) {
        const int k  = tid >> 5;            // 0..447
        const int c0 = (tid & 31) << 2;     // 0,4,...,124
        float4 v = {0.f, 0.f, 0.f, 0.f};
        if (k < 429) {
            v = *reinterpret_cast<const float4*>(&W_bottom[(k << 7) + c0]);
        }
        const int ks   = k >> 5;
        const int lhi  = (k >> 3) & 3;
        const int j    = k & 7;
        const float vv[4] = {v.x, v.y, v.z, v.w};
#pragma unroll
        for (int u = 0; u < 4; ++u) {
            const int c = c0 + u;
            const int n = c >> 4;
            const int l = (lhi << 4) | (c & 15);
            wsB[(((ks << 3) + n) * 64 + l) * 8 + j] = f2bf(vv[u]);
        }
    } else {
        const int t2 = tid - 448 * 32;
        if (t2 < 8 * 64) {                  // 4 ks2 x 2 n2 fragments
            const int frag = t2 >> 6;       // ks2*2 + n2
            const int l    = t2 & 63;
            const int ks2  = frag >> 1;
            const int n2   = frag & 1;
            const int hbase = (ks2 << 5) + ((l >> 4) << 3);
            const int col   = (n2 << 4) + (l & 15);
            const int d     = col >> 3;
            const int tt    = col & 7;
            unsigned long long lo = 0, hi = 0;
#pragma unroll
            for (int j = 0; j < 4; ++j) {
                lo |= (unsigned long long)f2bf(tower_W1[((d << 7) + hbase + j) * T_ + tt]) << (16 * j);
            }
#pragma unroll
            for (int j = 0; j < 4; ++j) {
                hi |= (unsigned long long)f2bf(tower_W1[((d << 7) + hbase + 4 + j) * T_ + tt]) << (16 * j);
            }
            ulonglong2 pack; pack.x = lo; pack.y = hi;
            *reinterpret_cast<ulonglong2*>(wsT1 + (size_t)t2 * 8) = pack;
        }
    }
}

// ---------- fused main kernel ----------
__global__ __launch_bounds__(NT, 4)
void sb_fused_kernel(const int* __restrict__ sparse_ids,
                     const float* __restrict__ dense,
                     const int* __restrict__ domain_id,
                     const float* __restrict__ emb_tables,
                     const float* __restrict__ b_bottom,
                     const float* __restrict__ tower_b1,
                     const float* __restrict__ tower_W2,
                     const float* __restrict__ tower_b2,
                     const unsigned short* __restrict__ wsB,
                     const unsigned short* __restrict__ wsT1,
                     float* __restrict__ out)
{
    __shared__ unsigned short x_lds[BB][XSTR];     // 29,184 B
    __shared__ unsigned short feat_lds[BB][FSTR];  //  8,704 B

    const int t  = threadIdx.x;
    const int r0 = blockIdx.x * BB;
    const int l   = t & 63;
    const int w   = t >> 6;        // 0..7
    const int lhi = l >> 4;        // 0..3
    const int llo = l & 15;

    const bf16x8* wsBv = reinterpret_cast<const bf16x8*>(wsB);

    // ---- step 1: issue the 7 sparse-id loads first (gather addr deps) ----
    int    ldsoff[NGT];
    int    id_[NGT];
    int    fq_[NGT];
#pragma unroll
    for (int it = 0; it < NGT; ++it) {
        const int idx = t + (it << 9);
        if (it < 6 || idx < BB * F_ * 4) {
            const int q   = idx & 3;
            const int rf  = idx >> 2;          // row * F_ + f
            const int row = rf / F_;
            const int f   = rf - row * F_;
            id_[it]    = sparse_ids[(r0 + row) * F_ + f];
            fq_[it]    = (f << 2) | q;
            ldsoff[it] = row * XSTR + (f << 4) + (q << 2);
        }
    }

    // ---- step 2: preload first NPRE B-fragments (latency hides under gather) ----
    bf16x8 bf_pre[NPRE];
#pragma unroll
    for (int ks = 0; ks < NPRE; ++ks) {
        bf_pre[ks] = wsBv[((ks << 3) + w) * 64 + l];
    }

    // ---- step 3: hand-pipelined gather (fp32 -> bf16) into LDS ----
    {
        float4 v_[NGT];
#pragma unroll
        for (int it = 0; it < NGT; ++it) {
            const int idx = t + (it << 9);
            if (it < 6 || idx < BB * F_ * 4) {
                const int f = fq_[it] >> 2;
                const int q = fq_[it] & 3;
                v_[it] = *reinterpret_cast<const float4*>(
                    emb_tables + ((size_t)f * V_ + (size_t)id_[it]) * E_ + (q << 2));
            }
        }
#pragma unroll
        for (int it = 0; it < NGT; ++it) {
            const int idx = t + (it << 9);
            if (it < 6 || idx < BB * F_ * 4) {
                ushort4 b;
                b.x = f2bf(v_[it].x); b.y = f2bf(v_[it].y);
                b.z = f2bf(v_[it].z); b.w = f2bf(v_[it].w);
                *reinterpret_cast<ushort4*>(&x_lds[0][0] + ldsoff[it]) = b;
            }
        }
    }
    // dense -> cols 416..428 (bf16), zero-pad cols 429..447 (2 tasks/thread)
#pragma unroll
    for (int it = 0; it < 2; ++it) {
        const int idx = t + (it << 9);
        const int row = idx >> 5;
        const int c   = 416 + (idx & 31);
        x_lds[row][c] = (c < 429) ? f2bf(dense[(r0 + row) * ND_ + (c - 416)]) : 0;
    }
    __syncthreads();

    // ---- Phase B: bottom GEMM via MFMA  feat = relu(X @ W + b) ----
    // wave w owns ntile w (cols 16w..16w+15), both mtiles (rows 0..31)
    f32x4 acc0 = {0.f,0.f,0.f,0.f};
    f32x4 acc1 = acc0;

#pragma unroll
    for (int ks = 0; ks < NKS; ++ks) {
        const int ko = (ks << 5) + (lhi << 3);
        const bf16x8 a0 = *reinterpret_cast<const bf16x8*>(&x_lds[llo][ko]);
        const bf16x8 a1 = *reinterpret_cast<const bf16x8*>(&x_lds[16 + llo][ko]);
        const bf16x8 b  = (ks < NPRE) ? bf_pre[ks] : wsBv[((ks << 3) + w) * 64 + l];
        acc0 = __builtin_amdgcn_mfma_f32_16x16x32_bf16(a0, b, acc0, 0, 0, 0);
        acc1 = __builtin_amdgcn_mfma_f32_16x16x32_bf16(a1, b, acc1, 0, 0, 0);
    }

    {   // epilogue: bias + relu -> feat_lds (bf16, A-fragment-friendly layout)
        const int c = (w << 4) + llo;
        const float bias = b_bottom[c];
#pragma unroll
        for (int i = 0; i < 4; ++i) {
            const int r = (lhi << 2) + i;
            feat_lds[r][c]      = f2bf(fmaxf(acc0[i] + bias, 0.f));
            feat_lds[16 + r][c] = f2bf(fmaxf(acc1[i] + bias, 0.f));
        }
    }
    __syncthreads();

    // ---- Phase C: tower via MFMA over all 4 domains (waves 0..3) ----
    // h_all[32 rows][32 cols], col = d*8 + tt.  wave w: mtile = w>>1, ntile = w&1
    if (w < 4) {
        const int mt = w >> 1;
        const int nt = w & 1;
        f32x4 acc = {0.f,0.f,0.f,0.f};
        const bf16x8* wsT1v = reinterpret_cast<const bf16x8*>(wsT1);
#pragma unroll
        for (int ks2 = 0; ks2 < 4; ++ks2) {
            const bf16x8 a = *reinterpret_cast<const bf16x8*>(
                &feat_lds[(mt << 4) + llo][(ks2 << 5) + (lhi << 3)]);
            const bf16x8 b = wsT1v[((ks2 << 1) + nt) * 64 + l];
            acc = __builtin_amdgcn_mfma_f32_16x16x32_bf16(a, b, acc, 0, 0, 0);
        }
        const int col    = (nt << 4) + llo;    // global tower col = d*8 + tt
        const float b1v  = tower_b1[col];
        const float w2v  = tower_W2[col];
        const int  dlane = (nt << 1) + (llo >> 3);
        const bool writer = ((llo & 7) == 0);
#pragma unroll
        for (int i = 0; i < 4; ++i) {
            float v = fmaxf(acc[i] + b1v, 0.f) * w2v;
            v += __shfl_xor(v, 1);
            v += __shfl_xor(v, 2);
            v += __shfl_xor(v, 4);
            if (writer) {
                const int r   = (mt << 4) + (lhi << 2) + i;
                const int d_r = domain_id[r0 + r];
                if (d_r == dlane) {
                    out[r0 + r] = 1.f / (1.f + expf(-(v + tower_b2[d_r])));
                }
            }
        }
    }
}

extern "C" void kernel_launch(void* const* d_in, const int* in_sizes, int n_in,
                              void* d_out, int out_size, void* d_ws, size_t ws_size,
                              hipStream_t stream) {
    const int*   sparse_ids = (const int*)  d_in[0];
    const float* dense      = (const float*)d_in[1];
    const int*   domain_id  = (const int*)  d_in[2];
    const float* emb_tables = (const float*)d_in[3];
    const float* W_bottom   = (const float*)d_in[4];
    const float* b_bottom   = (const float*)d_in[5];
    const float* tower_W1   = (const float*)d_in[6];
    const float* tower_b1   = (const float*)d_in[7];
    const float* tower_W2   = (const float*)d_in[8];
    const float* tower_b2   = (const float*)d_in[9];
    float* out = (float*)d_out;

    unsigned short* wsB  = (unsigned short*)d_ws;                    // 114,688 B
    unsigned short* wsT1 = (unsigned short*)((char*)d_ws + 131072);  //   8,192 B

    // prep v2: 14336 (coalesced W pack) + 512 (tower pack) threads
    prep_kernel<<<(448 * 32 + 8 * 64 + 255) / 256, 256, 0, stream>>>(
        W_bottom, tower_W1, wsB, wsT1);

    sb_fused_kernel<<<B_ / BB, NT, 0, stream>>>(
        sparse_ids, dense, domain_id, emb_tables,
        b_bottom, tower_b1, tower_W2, tower_b2, wsB, wsT1, out);
}